// Round 1
// baseline (379.282 us; speedup 1.0000x reference)
//
#include <hip/hip_runtime.h>
#include <hip/hip_bf16.h>
#include <cstdint>

#define B_  8192
#define I_  1024
#define H_  1024
#define R_  16
#define K_  2048   // I_ + H_
#define N_  4096   // 4 * H_

typedef __attribute__((ext_vector_type(4))) float f32x4;
typedef __attribute__((ext_vector_type(8))) __bf16 bf16x8;
typedef __attribute__((ext_vector_type(8))) unsigned short u16x8;
typedef unsigned short u16;

__device__ __forceinline__ u16 f2bf(float f) {
  union { float f; unsigned u; } v; v.f = f;
  unsigned u = v.u;
  return (u16)((u + 0x7fffu + ((u >> 16) & 1u)) >> 16);  // RNE
}

__device__ __forceinline__ float sigmoidf_(float x) {
  return 1.0f / (1.0f + __expf(-x));          // saturates cleanly, no NaN
}
__device__ __forceinline__ float tanhf_(float x) {
  return 1.0f - 2.0f / (__expf(2.0f * x) + 1.0f);  // inf-safe both tails
}

// ---------------- pack [x | h0] -> bf16 Xc[B][K] ----------------
__global__ __launch_bounds__(256) void prep_x(const float* __restrict__ x,
                                              const float* __restrict__ h0,
                                              u16* __restrict__ Xc) {
  int idx = blockIdx.x * 256 + threadIdx.x;   // grid 8192 -> 2M threads, 8 elems each
  int e = idx << 3;
  int b = e >> 11;
  int k = e & (K_ - 1);
  const float* src = (k < I_) ? (x + ((size_t)b << 10) + k)
                              : (h0 + ((size_t)b << 10) + (k - I_));
  const f32x4 v0 = *(const f32x4*)src;
  const f32x4 v1 = *(const f32x4*)(src + 4);
  u16x8 o;
  o[0] = f2bf(v0[0]); o[1] = f2bf(v0[1]); o[2] = f2bf(v0[2]); o[3] = f2bf(v0[3]);
  o[4] = f2bf(v1[0]); o[5] = f2bf(v1[1]); o[6] = f2bf(v1[2]); o[7] = f2bf(v1[3]);
  *(u16x8*)(Xc + (size_t)e) = o;
}

// ------- fold LoRA into weights, cast bf16, gate-interleaved rows n=h*4+g -------
__global__ __launch_bounds__(256) void prep_w(
    const float* __restrict__ W_i, const float* __restrict__ W_h,
    const float* __restrict__ b_i, const float* __restrict__ b_h,
    const float* __restrict__ A_i, const float* __restrict__ Bi,
    const float* __restrict__ A_h, const float* __restrict__ Bh,
    u16* __restrict__ Wc, float* __restrict__ bc) {
  const int gh = blockIdx.x;            // 4096 blocks = (g,h)
  const int g = gh >> 10, h = gh & (H_ - 1);
  const int tid = threadIdx.x;
  float bi[R_], bh[R_];
#pragma unroll
  for (int r = 0; r < R_; ++r) {
    bi[r] = Bi[((size_t)(g * H_ + h) << 4) + r];
    bh[r] = Bh[((size_t)(g * H_ + h) << 4) + r];
  }
  u16* dst = Wc + (size_t)(h * 4 + g) * K_;
  const float* wi = W_i + ((size_t)(g * H_ + h) << 10);
  const float* wh = W_h + ((size_t)(g * H_ + h) << 10);
#pragma unroll
  for (int it = 0; it < 4; ++it) {
    int k = it * 256 + tid;
    float acc = wi[k];
#pragma unroll
    for (int r = 0; r < R_; ++r) acc += bi[r] * A_i[((size_t)(g * R_ + r) << 10) + k];
    dst[k] = f2bf(acc);
  }
#pragma unroll
  for (int it = 0; it < 4; ++it) {
    int k = it * 256 + tid;
    float acc = wh[k];
#pragma unroll
    for (int r = 0; r < R_; ++r) acc += bh[r] * A_h[((size_t)(g * R_ + r) << 10) + k];
    dst[I_ + k] = f2bf(acc);
  }
  if (tid == 0) bc[h * 4 + g] = b_i[g * H_ + h] + b_h[g * H_ + h];
}

// ---------------- GEMM + fused LSTM gate epilogue ----------------
#define BM 128
#define BN 128
#define BK 64

#define GLOAD_LDS16(gp, lp)                                                        \
  __builtin_amdgcn_global_load_lds(                                                \
      (const __attribute__((address_space(1))) void*)(gp),                         \
      (__attribute__((address_space(3))) void*)(lp), 16, 0, 0)

__global__ __launch_bounds__(256) void lstm_gemm(
    const u16* __restrict__ Xc, const u16* __restrict__ Wc,
    const float* __restrict__ bc, const float* __restrict__ c0,
    float* __restrict__ out) {
  __shared__ u16 lA[BM * BK];   // 16 KB
  __shared__ u16 lB[BN * BK];   // 16 KB
  const int tid = threadIdx.x;
  const int wave = tid >> 6, lane = tid & 63;
  const int bn = blockIdx.x, bm = blockIdx.y;
  const int m0 = bm * BM, n0 = bn * BN;
  const int wm = (wave >> 1) * 64, wn = (wave & 1) * 64;
  const int lr = lane & 15, lk = lane >> 4;

  f32x4 acc[4][4] = {};

  const u16* Ag = Xc + (size_t)m0 * K_;
  const u16* Bg = Wc + (size_t)n0 * K_;

  for (int k0 = 0; k0 < K_; k0 += BK) {
    // stage A tile [128][64] bf16 (16 KB) : 1024 x 16B chunks, linear LDS
#pragma unroll
    for (int j = 0; j < 4; ++j) {
      int cid = j * 256 + tid;
      int row = cid >> 3, cc = cid & 7;
      GLOAD_LDS16(Ag + (size_t)row * K_ + k0 + cc * 8,
                  (char*)lA + (j * 256 + wave * 64) * 16);
    }
#pragma unroll
    for (int j = 0; j < 4; ++j) {
      int cid = j * 256 + tid;
      int row = cid >> 3, cc = cid & 7;
      GLOAD_LDS16(Bg + (size_t)row * K_ + k0 + cc * 8,
                  (char*)lB + (j * 256 + wave * 64) * 16);
    }
    __syncthreads();   // drains vmcnt before LDS reads

#pragma unroll
    for (int kk = 0; kk < 2; ++kk) {
      bf16x8 av[4], bv[4];
#pragma unroll
      for (int i = 0; i < 4; ++i)
        av[i] = *(const bf16x8*)&lA[(wm + i * 16 + lr) * BK + kk * 32 + lk * 8];
#pragma unroll
      for (int i = 0; i < 4; ++i)
        bv[i] = *(const bf16x8*)&lB[(wn + i * 16 + lr) * BK + kk * 32 + lk * 8];
#pragma unroll
      for (int mi = 0; mi < 4; ++mi)
#pragma unroll
        for (int ni = 0; ni < 4; ++ni)
          acc[mi][ni] = __builtin_amdgcn_mfma_f32_16x16x32_bf16(
              av[mi], bv[ni], acc[mi][ni], 0, 0, 0);
    }
    __syncthreads();
  }

  // fused epilogue: cols n = 4h+g (gate-interleaved). Gather the 4 gates of
  // each hidden unit across the 4-lane group, apply LSTM cell, store h_t/c_t.
#pragma unroll
  for (int ni = 0; ni < 4; ++ni) {
    const int n = n0 + wn + ni * 16 + lr;
    const float bias = bc[n];
    const int h = n >> 2;
#pragma unroll
    for (int mi = 0; mi < 4; ++mi) {
      const int rbase = m0 + wm + mi * 16 + lk * 4;
#pragma unroll
      for (int j = 0; j < 4; ++j) {
        float v = acc[mi][ni][j] + bias;
        const int src = lane & ~3;
        float pi = __shfl(v, src);
        float pf = __shfl(v, src | 1);
        float pg = __shfl(v, src | 2);
        float po = __shfl(v, src | 3);
        int row = rbase + j;
        float c0v = c0[(size_t)row * H_ + h];
        float ig = sigmoidf_(pi), fg = sigmoidf_(pf);
        float gg = tanhf_(pg),  og = sigmoidf_(po);
        float ct = fg * c0v + ig * gg;
        float ht = og * tanhf_(ct);
        if ((lane & 3) == 0) out[(size_t)row * H_ + h] = ht;
        if ((lane & 3) == 1) out[(size_t)(B_ * H_) + (size_t)row * H_ + h] = ct;
      }
    }
  }
}

extern "C" void kernel_launch(void* const* d_in, const int* in_sizes, int n_in,
                              void* d_out, int out_size, void* d_ws, size_t ws_size,
                              hipStream_t stream) {
  const float* x   = (const float*)d_in[0];
  const float* h0  = (const float*)d_in[1];
  const float* c0  = (const float*)d_in[2];
  const float* W_i = (const float*)d_in[3];
  const float* W_h = (const float*)d_in[4];
  const float* b_i = (const float*)d_in[5];
  const float* b_h = (const float*)d_in[6];
  const float* A_i = (const float*)d_in[7];
  const float* B_i = (const float*)d_in[8];
  const float* A_h = (const float*)d_in[9];
  const float* B_h = (const float*)d_in[10];
  float* out = (float*)d_out;

  char* ws = (char*)d_ws;
  u16*   Xc = (u16*)ws;                                   // 32 MB
  u16*   Wc = (u16*)(ws + ((size_t)32 << 20));            // 16 MB
  float* bc = (float*)(ws + ((size_t)48 << 20));          // 16 KB

  prep_x<<<dim3(B_ * K_ / 8 / 256), dim3(256), 0, stream>>>(x, h0, Xc);
  prep_w<<<dim3(4 * H_), dim3(256), 0, stream>>>(W_i, W_h, b_i, b_h,
                                                 A_i, B_i, A_h, B_h, Wc, bc);
  lstm_gemm<<<dim3(N_ / BN, B_ / BM), dim3(256), 0, stream>>>(Xc, Wc, bc, c0, out);
}

// Round 2
// 266.650 us; speedup vs baseline: 1.4224x; 1.4224x over previous
//
#include <hip/hip_runtime.h>
#include <hip/hip_bf16.h>
#include <cstdint>

#define B_  8192
#define I_  1024
#define H_  1024
#define R_  16
#define K_  2048   // I_ + H_
#define N_  4096   // 4 * H_

typedef __attribute__((ext_vector_type(4))) float f32x4;
typedef __attribute__((ext_vector_type(8))) __bf16 bf16x8;
typedef __attribute__((ext_vector_type(8))) unsigned short u16x8;
typedef unsigned short u16;

__device__ __forceinline__ u16 f2bf(float f) {
  union { float f; unsigned u; } v; v.f = f;
  unsigned u = v.u;
  return (u16)((u + 0x7fffu + ((u >> 16) & 1u)) >> 16);  // RNE
}

__device__ __forceinline__ float sigmoidf_(float x) {
  return 1.0f / (1.0f + __expf(-x));          // saturates cleanly, no NaN
}
__device__ __forceinline__ float tanhf_(float x) {
  return 1.0f - 2.0f / (__expf(2.0f * x) + 1.0f);  // inf-safe both tails
}

// ---------------- pack [x | h0] -> bf16 Xc[B][K] ----------------
__global__ __launch_bounds__(256) void prep_x(const float* __restrict__ x,
                                              const float* __restrict__ h0,
                                              u16* __restrict__ Xc) {
  int idx = blockIdx.x * 256 + threadIdx.x;   // 2M threads, 8 elems each
  int e = idx << 3;
  int b = e >> 11;
  int k = e & (K_ - 1);
  const float* src = (k < I_) ? (x + ((size_t)b << 10) + k)
                              : (h0 + ((size_t)b << 10) + (k - I_));
  const f32x4 v0 = *(const f32x4*)src;
  const f32x4 v1 = *(const f32x4*)(src + 4);
  u16x8 o;
  o[0] = f2bf(v0[0]); o[1] = f2bf(v0[1]); o[2] = f2bf(v0[2]); o[3] = f2bf(v0[3]);
  o[4] = f2bf(v1[0]); o[5] = f2bf(v1[1]); o[6] = f2bf(v1[2]); o[7] = f2bf(v1[3]);
  *(u16x8*)(Xc + (size_t)e) = o;
}

// ------- fold LoRA into weights, cast bf16, gate-interleaved rows n=h*4+g -------
__global__ __launch_bounds__(256) void prep_w(
    const float* __restrict__ W_i, const float* __restrict__ W_h,
    const float* __restrict__ b_i, const float* __restrict__ b_h,
    const float* __restrict__ A_i, const float* __restrict__ Bi,
    const float* __restrict__ A_h, const float* __restrict__ Bh,
    u16* __restrict__ Wc, float* __restrict__ bc) {
  const int gh = blockIdx.x;            // 4096 blocks = (g,h)
  const int g = gh >> 10, h = gh & (H_ - 1);
  const int tid = threadIdx.x;
  float bi[R_], bh[R_];
#pragma unroll
  for (int r = 0; r < R_; ++r) {
    bi[r] = Bi[((size_t)(g * H_ + h) << 4) + r];
    bh[r] = Bh[((size_t)(g * H_ + h) << 4) + r];
  }
  u16* dst = Wc + (size_t)(h * 4 + g) * K_;
  const float* wi = W_i + ((size_t)(g * H_ + h) << 10);
  const float* wh = W_h + ((size_t)(g * H_ + h) << 10);
#pragma unroll
  for (int it = 0; it < 4; ++it) {
    int k = it * 256 + tid;
    float acc = wi[k];
#pragma unroll
    for (int r = 0; r < R_; ++r) acc += bi[r] * A_i[((size_t)(g * R_ + r) << 10) + k];
    dst[k] = f2bf(acc);
  }
#pragma unroll
  for (int it = 0; it < 4; ++it) {
    int k = it * 256 + tid;
    float acc = wh[k];
#pragma unroll
    for (int r = 0; r < R_; ++r) acc += bh[r] * A_h[((size_t)(g * R_ + r) << 10) + k];
    dst[I_ + k] = f2bf(acc);
  }
  if (tid == 0) bc[h * 4 + g] = b_i[g * H_ + h] + b_h[g * H_ + h];
}

// ---------------- GEMM + fused LSTM gate epilogue ----------------
#define BM 128
#define BN 128
#define BK 64

#define GLOAD_LDS16(gp, lp)                                                        \
  __builtin_amdgcn_global_load_lds(                                                \
      (const __attribute__((address_space(1))) void*)(gp),                         \
      (__attribute__((address_space(3))) void*)(lp), 16, 0, 0)

__global__ __launch_bounds__(256) void lstm_gemm(
    const u16* __restrict__ Xc, const u16* __restrict__ Wc,
    const float* __restrict__ bc, const float* __restrict__ c0,
    float* __restrict__ out) {
  __shared__ u16 lds_u16[BM * BK + BN * BK];   // 32 KB
  u16* lA = lds_u16;
  u16* lB = lds_u16 + BM * BK;
  const int tid = threadIdx.x;
  const int wave = tid >> 6, lane = tid & 63;
  const int bn = blockIdx.x, bm = blockIdx.y;
  const int m0 = bm * BM, n0 = bn * BN;
  const int wm = (wave >> 1) * 64, wn = (wave & 1) * 64;
  const int lr = lane & 15, lk = lane >> 4;

  f32x4 acc[4][4] = {};

  const u16* Ag = Xc + (size_t)m0 * K_;
  const u16* Bg = Wc + (size_t)n0 * K_;

  for (int k0 = 0; k0 < K_; k0 += BK) {
    // stage tiles [128][64] bf16: LDS dest linear (global_load_lds rule);
    // T2 swizzle applied by permuting which GLOBAL chunk each lane fetches.
#pragma unroll
    for (int j = 0; j < 4; ++j) {
      int cid = j * 256 + tid;
      int row = cid >> 3, cp = cid & 7;
      int cc = cp ^ (row & 7);             // inverse-swizzled source chunk
      GLOAD_LDS16(Ag + (size_t)row * K_ + k0 + cc * 8,
                  (char*)lA + (j * 256 + wave * 64) * 16);
    }
#pragma unroll
    for (int j = 0; j < 4; ++j) {
      int cid = j * 256 + tid;
      int row = cid >> 3, cp = cid & 7;
      int cc = cp ^ (row & 7);
      GLOAD_LDS16(Bg + (size_t)row * K_ + k0 + cc * 8,
                  (char*)lB + (j * 256 + wave * 64) * 16);
    }
    __syncthreads();   // drains vmcnt before LDS reads

#pragma unroll
    for (int kk = 0; kk < 2; ++kk) {
      bf16x8 av[4], bv[4];
#pragma unroll
      for (int i = 0; i < 4; ++i) {
        int r = wm + i * 16 + lr;
        av[i] = *(const bf16x8*)&lA[r * 64 + (((kk * 4 + lk) ^ (r & 7)) << 3)];
      }
#pragma unroll
      for (int i = 0; i < 4; ++i) {
        int r = wn + i * 16 + lr;
        bv[i] = *(const bf16x8*)&lB[r * 64 + (((kk * 4 + lk) ^ (r & 7)) << 3)];
      }
#pragma unroll
      for (int mi = 0; mi < 4; ++mi)
#pragma unroll
        for (int ni = 0; ni < 4; ++ni)
          acc[mi][ni] = __builtin_amdgcn_mfma_f32_16x16x32_bf16(
              av[mi], bv[ni], acc[mi][ni], 0, 0, 0);
    }
    __syncthreads();
  }

  // ---- fused epilogue via LDS transpose (2 halves of 64 rows x 128 gate-cols).
  // cols n = 4h+g (gate-interleaved) -> each (row,h)'s 4 gates are one f32x4.
  float* lE = (float*)lds_u16;          // 8192 floats = 32 KB
  const int hbase = n0 >> 2;            // 32 h-units per block
#pragma unroll
  for (int half = 0; half < 2; ++half) {
    __syncthreads();
#pragma unroll
    for (int mio = 0; mio < 2; ++mio) {
      int mi = half * 2 + mio;
#pragma unroll
      for (int ni = 0; ni < 4; ++ni) {
        int n_local = wn + ni * 16 + lr;
        float bias = bc[n0 + n_local];
#pragma unroll
        for (int j = 0; j < 4; ++j) {
          int lrow = (wave >> 1) * 32 + mio * 16 + lk * 4 + j;
          lE[lrow * 128 + n_local] = acc[mi][ni][j] + bias;
        }
      }
    }
    __syncthreads();
#pragma unroll
    for (int jj = 0; jj < 8; ++jj) {
      int item = jj * 256 + tid;
      int hh = item & 31;               // h' within block
      int lrow = item >> 5;             // 0..63
      f32x4 pre = *(const f32x4*)&lE[lrow * 128 + hh * 4];
      int grow = m0 + (lrow >> 5) * 64 + half * 32 + (lrow & 31);
      int hg = hbase + hh;
      float c0v = c0[(size_t)grow * H_ + hg];
      float ig = sigmoidf_(pre[0]);
      float fg = sigmoidf_(pre[1]);
      float gg = tanhf_(pre[2]);
      float og = sigmoidf_(pre[3]);
      float ct = fg * c0v + ig * gg;
      float ht = og * tanhf_(ct);
      out[(size_t)grow * H_ + hg] = ht;
      out[(size_t)(B_ * H_) + (size_t)grow * H_ + hg] = ct;
    }
  }
}

extern "C" void kernel_launch(void* const* d_in, const int* in_sizes, int n_in,
                              void* d_out, int out_size, void* d_ws, size_t ws_size,
                              hipStream_t stream) {
  const float* x   = (const float*)d_in[0];
  const float* h0  = (const float*)d_in[1];
  const float* c0  = (const float*)d_in[2];
  const float* W_i = (const float*)d_in[3];
  const float* W_h = (const float*)d_in[4];
  const float* b_i = (const float*)d_in[5];
  const float* b_h = (const float*)d_in[6];
  const float* A_i = (const float*)d_in[7];
  const float* B_i = (const float*)d_in[8];
  const float* A_h = (const float*)d_in[9];
  const float* B_h = (const float*)d_in[10];
  float* out = (float*)d_out;

  char* ws = (char*)d_ws;
  u16*   Xc = (u16*)ws;                                   // 32 MB
  u16*   Wc = (u16*)(ws + ((size_t)32 << 20));            // 16 MB
  float* bc = (float*)(ws + ((size_t)48 << 20));          // 16 KB

  prep_x<<<dim3(B_ * K_ / 8 / 256), dim3(256), 0, stream>>>(x, h0, Xc);
  prep_w<<<dim3(4 * H_), dim3(256), 0, stream>>>(W_i, W_h, b_i, b_h,
                                                 A_i, B_i, A_h, B_h, Wc, bc);
  lstm_gemm<<<dim3(N_ / BN, B_ / BM), dim3(256), 0, stream>>>(Xc, Wc, bc, c0, out);
}

// Round 3
// 232.646 us; speedup vs baseline: 1.6303x; 1.1462x over previous
//
#include <hip/hip_runtime.h>
#include <hip/hip_bf16.h>
#include <cstdint>

#define B_  8192
#define I_  1024
#define H_  1024
#define R_  16
#define K_  2048   // I_ + H_
#define N_  4096   // 4 * H_

typedef __attribute__((ext_vector_type(4))) float f32x4;
typedef __attribute__((ext_vector_type(8))) __bf16 bf16x8;
typedef __attribute__((ext_vector_type(8))) unsigned short u16x8;
typedef unsigned short u16;

__device__ __forceinline__ u16 f2bf(float f) {
  union { float f; unsigned u; } v; v.f = f;
  unsigned u = v.u;
  return (u16)((u + 0x7fffu + ((u >> 16) & 1u)) >> 16);  // RNE
}

__device__ __forceinline__ float sigmoidf_(float x) {
  return 1.0f / (1.0f + __expf(-x));
}
__device__ __forceinline__ float tanhf_(float x) {
  return 1.0f - 2.0f / (__expf(2.0f * x) + 1.0f);  // inf-safe both tails
}

// ---------------- pack [x | h0] -> bf16 Xc[B][K] ----------------
__global__ __launch_bounds__(256) void prep_x(const float* __restrict__ x,
                                              const float* __restrict__ h0,
                                              u16* __restrict__ Xc) {
  int idx = blockIdx.x * 256 + threadIdx.x;
  int e = idx << 3;
  int b = e >> 11;
  int k = e & (K_ - 1);
  const float* src = (k < I_) ? (x + ((size_t)b << 10) + k)
                              : (h0 + ((size_t)b << 10) + (k - I_));
  const f32x4 v0 = *(const f32x4*)src;
  const f32x4 v1 = *(const f32x4*)(src + 4);
  u16x8 o;
  o[0] = f2bf(v0[0]); o[1] = f2bf(v0[1]); o[2] = f2bf(v0[2]); o[3] = f2bf(v0[3]);
  o[4] = f2bf(v1[0]); o[5] = f2bf(v1[1]); o[6] = f2bf(v1[2]); o[7] = f2bf(v1[3]);
  *(u16x8*)(Xc + (size_t)e) = o;
}

// ------- fold LoRA into weights, cast bf16, gate-interleaved rows n=h*4+g -------
__global__ __launch_bounds__(256) void prep_w(
    const float* __restrict__ W_i, const float* __restrict__ W_h,
    const float* __restrict__ b_i, const float* __restrict__ b_h,
    const float* __restrict__ A_i, const float* __restrict__ Bi,
    const float* __restrict__ A_h, const float* __restrict__ Bh,
    u16* __restrict__ Wc, float* __restrict__ bc) {
  const int gh = blockIdx.x;            // 4096 blocks = (g,h)
  const int g = gh >> 10, h = gh & (H_ - 1);
  const int tid = threadIdx.x;
  float bi[R_], bh[R_];
#pragma unroll
  for (int r = 0; r < R_; ++r) {
    bi[r] = Bi[((size_t)(g * H_ + h) << 4) + r];
    bh[r] = Bh[((size_t)(g * H_ + h) << 4) + r];
  }
  u16* dst = Wc + (size_t)(h * 4 + g) * K_;
  const float* wi = W_i + ((size_t)(g * H_ + h) << 10);
  const float* wh = W_h + ((size_t)(g * H_ + h) << 10);
#pragma unroll
  for (int it = 0; it < 4; ++it) {
    int k = it * 256 + tid;
    float acc = wi[k];
#pragma unroll
    for (int r = 0; r < R_; ++r) acc += bi[r] * A_i[((size_t)(g * R_ + r) << 10) + k];
    dst[k] = f2bf(acc);
  }
#pragma unroll
  for (int it = 0; it < 4; ++it) {
    int k = it * 256 + tid;
    float acc = wh[k];
#pragma unroll
    for (int r = 0; r < R_; ++r) acc += bh[r] * A_h[((size_t)(g * R_ + r) << 10) + k];
    dst[I_ + k] = f2bf(acc);
  }
  if (tid == 0) bc[h * 4 + g] = b_i[g * H_ + h] + b_h[g * H_ + h];
}

// ---------------- 256x256 deep-pipelined GEMM + fused LSTM epilogue ----------------
#define BM 256
#define BN 256
#define BK 64
#define NT (K_ / BK)   // 32 K-tiles

#define GLOAD_LDS16(gp, lp)                                                        \
  __builtin_amdgcn_global_load_lds(                                                \
      (const __attribute__((address_space(1))) void*)(gp),                         \
      (__attribute__((address_space(3))) void*)(lp), 16, 0, 0)

#define BAR()                                                                      \
  do { asm volatile("" ::: "memory"); __builtin_amdgcn_s_barrier();                \
       asm volatile("" ::: "memory"); } while (0)

#define BARL()                                                                     \
  do { asm volatile("s_waitcnt lgkmcnt(0)" ::: "memory");                          \
       __builtin_amdgcn_s_barrier(); asm volatile("" ::: "memory"); } while (0)

#define WAITV0() asm volatile("s_waitcnt vmcnt(0)" ::: "memory")

// stage one round: each thread 1x16B chunk; source chunk XOR-swizzled so the
// linear global_load_lds dest matches the swizzled read layout (rule #21).
#define STAGE4(GBASE, K0N, LDST)                                                   \
  _Pragma("unroll")                                                                \
  for (int r_ = 0; r_ < 4; ++r_) {                                                 \
    int chunk_ = r_ * 512 + tid;                                                   \
    int row_ = chunk_ >> 3, cp_ = chunk_ & 7;                                      \
    int cc_ = cp_ ^ (row_ & 7);                                                    \
    GLOAD_LDS16((GBASE) + (size_t)row_ * K_ + (K0N) + cc_ * 8,                     \
                (char*)(LDST) + chunk_ * 16);                                      \
  }

#define READ_A(MH, LAC)                                                            \
  _Pragma("unroll")                                                                \
  for (int mi_ = 0; mi_ < 4; ++mi_) {                                              \
    _Pragma("unroll")                                                              \
    for (int kk_ = 0; kk_ < 2; ++kk_) {                                            \
      const int row_ = wm + ((MH) * 4 + mi_) * 16 + lr;                            \
      av[mi_][kk_] = *(const bf16x8*)&(LAC)[row_ * 64 +                            \
          (((kk_ * 4 + lk) ^ (row_ & 7)) << 3)];                                   \
    }                                                                              \
  }

#define READ_B(NH, BV, LBC)                                                        \
  _Pragma("unroll")                                                                \
  for (int nj_ = 0; nj_ < 2; ++nj_) {                                              \
    _Pragma("unroll")                                                              \
    for (int kk_ = 0; kk_ < 2; ++kk_) {                                            \
      const int row_ = wnl + ((NH) * 2 + nj_) * 16 + lr;                           \
      BV[nj_][kk_] = *(const bf16x8*)&(LBC)[row_ * 64 +                            \
          (((kk_ * 4 + lk) ^ (row_ & 7)) << 3)];                                   \
    }                                                                              \
  }

#define MMA(MH, NH, BV)                                                            \
  do {                                                                             \
    __builtin_amdgcn_s_setprio(1);                                                 \
    _Pragma("unroll")                                                              \
    for (int mi_ = 0; mi_ < 4; ++mi_)                                              \
      _Pragma("unroll")                                                            \
      for (int nj_ = 0; nj_ < 2; ++nj_)                                            \
        _Pragma("unroll")                                                          \
        for (int kk_ = 0; kk_ < 2; ++kk_)                                          \
          acc[(MH) * 4 + mi_][(NH) * 2 + nj_] =                                    \
              __builtin_amdgcn_mfma_f32_16x16x32_bf16(                             \
                  av[mi_][kk_], BV[nj_][kk_],                                      \
                  acc[(MH) * 4 + mi_][(NH) * 2 + nj_], 0, 0, 0);                   \
    __builtin_amdgcn_s_setprio(0);                                                 \
  } while (0)

// One K-tile: 4 phases (mh,nh); stages for NEXT tile issued in phases 0-1 into
// the other buffer; single counted drain after phase-3 MFMA (covered by ~3
// phases of MFMA since last issue).
#define KTILE(LAC, LBC, LAN, LBN, K0N, PF)                                         \
  do {                                                                             \
    READ_A(0, LAC);                                                                \
    READ_B(0, bv0, LBC);                                                           \
    if (PF) { STAGE4(Ag, K0N, LAN); }                                              \
    BAR(); MMA(0, 0, bv0); BAR();                                                  \
    READ_B(1, bv1, LBC);                                                           \
    if (PF) { STAGE4(Bg, K0N, LBN); }                                              \
    BAR(); MMA(0, 1, bv1); BAR();                                                  \
    READ_A(1, LAC);                                                                \
    BAR(); MMA(1, 0, bv0); BAR();                                                  \
    MMA(1, 1, bv1);                                                                \
    if (PF) { WAITV0(); }                                                          \
    BAR();                                                                         \
  } while (0)

__global__ __launch_bounds__(512, 2) void lstm_gemm(
    const u16* __restrict__ Xc, const u16* __restrict__ Wc,
    const float* __restrict__ bc, const float* __restrict__ c0,
    float* __restrict__ out) {
  __shared__ __align__(16) char lds_raw[131072];  // 2 x (A 32KB + B 32KB)
  u16* lA0 = (u16*)lds_raw;
  u16* lB0 = (u16*)(lds_raw + 32768);
  u16* lA1 = (u16*)(lds_raw + 65536);
  u16* lB1 = (u16*)(lds_raw + 98304);

  const int tid = threadIdx.x;
  const int wave = tid >> 6, lane = tid & 63;
  const int lr = lane & 15, lk = lane >> 4;
  const int bn = blockIdx.x, bm = blockIdx.y;
  const int m0 = bm * BM, n0 = bn * BN;
  const int wm = (wave >> 2) * 128;   // 2 M-warps
  const int wnl = (wave & 3) * 64;    // 4 N-warps

  f32x4 acc[8][4] = {};
  bf16x8 av[4][2], bv0[2][2], bv1[2][2];

  const u16* Ag = Xc + (size_t)m0 * K_;
  const u16* Bg = Wc + (size_t)n0 * K_;

  // prologue: stage tile 0 into buf0, full drain once
  STAGE4(Ag, 0, lA0);
  STAGE4(Bg, 0, lB0);
  WAITV0();
  BAR();

#pragma unroll 1
  for (int tt = 0; tt < NT / 2; ++tt) {
    KTILE(lA0, lB0, lA1, lB1, tt * 128 + 64, 1);
    KTILE(lA1, lB1, lA0, lB0, tt * 128 + 128, (tt < NT / 2 - 1));
  }

  // ---- fused epilogue: 2 halves of 128 rows x 256 gate-cols via LDS transpose
  float* lE = (float*)lds_raw;        // [128][256] f32 = 128 KB
  float biasv[4];
#pragma unroll
  for (int ni = 0; ni < 4; ++ni) biasv[ni] = bc[n0 + wnl + ni * 16 + lr];

#pragma unroll
  for (int half = 0; half < 2; ++half) {
    BARL();
    if ((wave >> 2) == half) {
#pragma unroll
      for (int mi = 0; mi < 8; ++mi)
#pragma unroll
        for (int ni = 0; ni < 4; ++ni)
#pragma unroll
          for (int j = 0; j < 4; ++j)
            lE[(mi * 16 + lk * 4 + j) * 256 + wnl + ni * 16 + lr] =
                acc[mi][ni][j] + biasv[ni];
    }
    BARL();
#pragma unroll
    for (int jj = 0; jj < 16; ++jj) {
      int item = jj * 512 + tid;
      int hl = item & 63, r = item >> 6;
      f32x4 pre = *(const f32x4*)&lE[r * 256 + hl * 4];
      int grow = m0 + half * 128 + r;
      int hg = (n0 >> 2) + hl;
      float c0v = c0[(size_t)grow * H_ + hg];
      float ig = sigmoidf_(pre[0]);
      float fg = sigmoidf_(pre[1]);
      float gg = tanhf_(pre[2]);
      float og = sigmoidf_(pre[3]);
      float ct = fg * c0v + ig * gg;
      float ht = og * tanhf_(ct);
      out[(size_t)grow * H_ + hg] = ht;
      out[(size_t)(B_ * H_) + (size_t)grow * H_ + hg] = ct;
    }
  }
}

extern "C" void kernel_launch(void* const* d_in, const int* in_sizes, int n_in,
                              void* d_out, int out_size, void* d_ws, size_t ws_size,
                              hipStream_t stream) {
  const float* x   = (const float*)d_in[0];
  const float* h0  = (const float*)d_in[1];
  const float* c0  = (const float*)d_in[2];
  const float* W_i = (const float*)d_in[3];
  const float* W_h = (const float*)d_in[4];
  const float* b_i = (const float*)d_in[5];
  const float* b_h = (const float*)d_in[6];
  const float* A_i = (const float*)d_in[7];
  const float* B_i = (const float*)d_in[8];
  const float* A_h = (const float*)d_in[9];
  const float* B_h = (const float*)d_in[10];
  float* out = (float*)d_out;

  char* ws = (char*)d_ws;
  u16*   Xc = (u16*)ws;                                   // 32 MB
  u16*   Wc = (u16*)(ws + ((size_t)32 << 20));            // 16 MB
  float* bc = (float*)(ws + ((size_t)48 << 20));          // 16 KB

  prep_x<<<dim3(B_ * K_ / 8 / 256), dim3(256), 0, stream>>>(x, h0, Xc);
  prep_w<<<dim3(4 * H_), dim3(256), 0, stream>>>(W_i, W_h, b_i, b_h,
                                                 A_i, B_i, A_h, B_h, Wc, bc);
  lstm_gemm<<<dim3(N_ / BN, B_ / BM), dim3(512), 0, stream>>>(Xc, Wc, bc, c0, out);
}